// Round 5
// baseline (74.994 us; speedup 1.0000x reference)
//
#include <hip/hip_runtime.h>
#include <stdint.h>

// Problem constants (fixed by setup_inputs)
#define NB 8
#define NC 32
#define NK 36
// u: (8,32,64,64) fp32; rfs: (36,64,64) binary fp32; out: (8,32,36,32,32) fp32 = 36.9 MB.
// Memory-bound: write floor ~6 us at 6.2 TB/s (poison fills demonstrate that rate).
//
// Single kernel, no LDS, no barrier. block = (bc-pair, kgroup-of-4).
// grid = 128 pairs x 9 kgroups = 1152 blocks (4.5 blocks/CU, ~18 waves/CU).
// Thread t: oh = t>>3 (0..31), ow4 = t&7 -> input rows 2*oh..2*oh+1,
// cols 8*ow4..8*ow4+7 (float4 index pos..pos+1 and pos+16..pos+17).
// Each thread: 8 u float4 loads (2 planes), 16 rfs float4 loads (4 k),
// packs 4x 16-bit masks in registers, 8 coalesced float4 stores.

__global__ __launch_bounds__(256) void pool_fused(const float4* __restrict__ u4,
                                                  const float4* __restrict__ rfs4,
                                                  float4* __restrict__ out4) {
    const int bid = blockIdx.x;          // 0..1151
    const int pair = bid / 9;            // 0..127 (bc pair)
    const int kg = bid - pair * 9;       // 0..8
    const int k0 = kg * 4;
    const int t = threadIdx.x;
    const int pos = (t >> 3) * 32 + (t & 7) * 2;   // float4 index in 64x64 plane

    // u loads: 2 bc planes, issued first (longest latency)
    const int bc0 = pair * 2;
    const int ub0 = bc0 * 1024 + pos;
    const int ub1 = ub0 + 1024;
    float4 a0 = u4[ub0], a1 = u4[ub0 + 1], b0 = u4[ub0 + 16], b1 = u4[ub0 + 17];
    float4 c0 = u4[ub1], c1 = u4[ub1 + 1], d0 = u4[ub1 + 16], d1 = u4[ub1 + 17];

    // pack 4 RF masks into registers (rfs is L2/L3-resident)
    unsigned m[4];
    #pragma unroll
    for (int kk = 0; kk < 4; ++kk) {
        const int rb = (k0 + kk) * 1024 + pos;
        float4 r0a = rfs4[rb];        // row 2*oh,   cols 0..3 of 8-col slab
        float4 r0b = rfs4[rb + 1];    // row 2*oh,   cols 4..7
        float4 r1a = rfs4[rb + 16];   // row 2*oh+1, cols 0..3
        float4 r1b = rfs4[rb + 17];   // row 2*oh+1, cols 4..7
        unsigned mm = 0;
        mm |= (unsigned)(r0a.x > 0.5f) << 0;
        mm |= (unsigned)(r0a.y > 0.5f) << 1;
        mm |= (unsigned)(r0a.z > 0.5f) << 2;
        mm |= (unsigned)(r0a.w > 0.5f) << 3;
        mm |= (unsigned)(r0b.x > 0.5f) << 4;
        mm |= (unsigned)(r0b.y > 0.5f) << 5;
        mm |= (unsigned)(r0b.z > 0.5f) << 6;
        mm |= (unsigned)(r0b.w > 0.5f) << 7;
        mm |= (unsigned)(r1a.x > 0.5f) << 8;
        mm |= (unsigned)(r1a.y > 0.5f) << 9;
        mm |= (unsigned)(r1a.z > 0.5f) << 10;
        mm |= (unsigned)(r1a.w > 0.5f) << 11;
        mm |= (unsigned)(r1b.x > 0.5f) << 12;
        mm |= (unsigned)(r1b.y > 0.5f) << 13;
        mm |= (unsigned)(r1b.z > 0.5f) << 14;
        mm |= (unsigned)(r1b.w > 0.5f) << 15;
        m[kk] = mm;
    }

    const int ob0 = (bc0 * NK + k0) * 256 + t;   // float4 index into output
    const int ob1 = ob0 + NK * 256;              // next bc plane

    #pragma unroll
    for (int kk = 0; kk < 4; ++kk) {
        const unsigned mm = m[kk];
        float4 o;
        o.x = (mm & 0x0001u ? a0.x : 0.f) + (mm & 0x0002u ? a0.y : 0.f)
            + (mm & 0x0100u ? b0.x : 0.f) + (mm & 0x0200u ? b0.y : 0.f);
        o.y = (mm & 0x0004u ? a0.z : 0.f) + (mm & 0x0008u ? a0.w : 0.f)
            + (mm & 0x0400u ? b0.z : 0.f) + (mm & 0x0800u ? b0.w : 0.f);
        o.z = (mm & 0x0010u ? a1.x : 0.f) + (mm & 0x0020u ? a1.y : 0.f)
            + (mm & 0x1000u ? b1.x : 0.f) + (mm & 0x2000u ? b1.y : 0.f);
        o.w = (mm & 0x0040u ? a1.z : 0.f) + (mm & 0x0080u ? a1.w : 0.f)
            + (mm & 0x4000u ? b1.z : 0.f) + (mm & 0x8000u ? b1.w : 0.f);
        out4[ob0 + kk * 256] = o;

        float4 p;
        p.x = (mm & 0x0001u ? c0.x : 0.f) + (mm & 0x0002u ? c0.y : 0.f)
            + (mm & 0x0100u ? d0.x : 0.f) + (mm & 0x0200u ? d0.y : 0.f);
        p.y = (mm & 0x0004u ? c0.z : 0.f) + (mm & 0x0008u ? c0.w : 0.f)
            + (mm & 0x0400u ? d0.z : 0.f) + (mm & 0x0800u ? d0.w : 0.f);
        p.z = (mm & 0x0010u ? c1.x : 0.f) + (mm & 0x0020u ? c1.y : 0.f)
            + (mm & 0x1000u ? d1.x : 0.f) + (mm & 0x2000u ? d1.y : 0.f);
        p.w = (mm & 0x0040u ? c1.z : 0.f) + (mm & 0x0080u ? c1.w : 0.f)
            + (mm & 0x4000u ? d1.z : 0.f) + (mm & 0x8000u ? d1.w : 0.f);
        out4[ob1 + kk * 256] = p;
    }
}

extern "C" void kernel_launch(void* const* d_in, const int* in_sizes, int n_in,
                              void* d_out, int out_size, void* d_ws, size_t ws_size,
                              hipStream_t stream) {
    const float* u = (const float*)d_in[0];     // (8,32,64,64)
    const float* rfs = (const float*)d_in[1];   // (36,64,64)
    float* out = (float*)d_out;                 // (8,32,36,32,32)

    // 128 bc-pairs x 9 kgroups-of-4 = 1152 blocks
    pool_fused<<<1152, 256, 0, stream>>>((const float4*)u, (const float4*)rfs, (float4*)out);
}